// Round 5
// baseline (695.112 us; speedup 1.0000x reference)
//
#include <hip/hip_runtime.h>

#define L 2048
#define D 1024
#define H 16
#define Z 64
#define HZ 1024

typedef __bf16 bf16x8 __attribute__((ext_vector_type(8)));
typedef float f32x4 __attribute__((ext_vector_type(4)));
typedef float f32x16 __attribute__((ext_vector_type(16)));

// ---------------------------------------------------------------------------
// Tile staging layout (64 rows x 64 bf16 = 8 KB), fragment-ordered:
//   piece it (0..1) of thread: region = it*4 + wave; row = (region>>1)*16 + (l&15);
//   col8 = (region&1)*4 + (l>>4); LDS byte offset = region*1024 + l*16.
// Fragment reads at (row, col8) are the inverse; writes/reads conflict-free.
// ---------------------------------------------------------------------------
__device__ __forceinline__ bf16x8 frag(const char* lds, int blk, int t, int lane) {
  return *(const bf16x8*)(lds + (((blk << 1) + t) << 10) + (lane << 4));
}

__device__ __forceinline__ bf16x8 rfrag(const char* lds, int row, int cc) {
  const int region = ((row >> 4) << 1) + (cc >> 2);
  const int slot = (row & 15) + ((cc & 3) << 4);
  return *(const bf16x8*)(lds + region * 1024 + slot * 16);
}

// per-thread staging piece geometry
struct StagePiece { int r, c, loff; };
__device__ __forceinline__ StagePiece piece_of(int tid, int it) {
  const int l = tid & 63, w = tid >> 6;
  const int region = it * 4 + w;
  StagePiece p;
  p.r = ((region >> 1) << 4) + (l & 15);
  p.c = ((region & 1) << 2) + (l >> 4);
  p.loff = (region << 10) + (l << 4);
  return p;
}

// ---------------------------------------------------------------------------
// fp32 -> bf16 flat convert (n4 = n/4)
// ---------------------------------------------------------------------------
__global__ __launch_bounds__(256) void cvt_kernel(const float* __restrict__ s,
                                                  __bf16* __restrict__ d, int n4) {
  int i = blockIdx.x * 256 + threadIdx.x;
  if (i < n4) {
    float4 v = ((const float4*)s)[i];
    union { __bf16 h[4]; uint2 u; } o;
    o.h[0] = (__bf16)v.x; o.h[1] = (__bf16)v.y;
    o.h[2] = (__bf16)v.z; o.h[3] = (__bf16)v.w;
    ((uint2*)d)[i] = o.u;
  }
}

// ---------------------------------------------------------------------------
// W (fp32) -> Wb (bf16, straight) + Wt (bf16, transposed)
// ---------------------------------------------------------------------------
__global__ __launch_bounds__(256) void wt_kernel(
    const float* __restrict__ Wk, const float* __restrict__ Wq,
    __bf16* __restrict__ Wkb, __bf16* __restrict__ Wqb,
    __bf16* __restrict__ Wkt, __bf16* __restrict__ Wqt) {
  const float* W = blockIdx.z ? Wq : Wk;
  __bf16* Wb = blockIdx.z ? Wqb : Wkb;
  __bf16* Wt = blockIdx.z ? Wqt : Wkt;
  __shared__ __bf16 tile[64][65];
  const int r0 = blockIdx.y * 64, c0 = blockIdx.x * 64;
  const int c = threadIdx.x & 63, rb = threadIdx.x >> 6;
#pragma unroll
  for (int i = 0; i < 16; ++i) {
    int r = rb + i * 4;
    __bf16 v = (__bf16)W[(size_t)(r0 + r) * D + c0 + c];
    tile[r][c] = v;
    Wb[(size_t)(r0 + r) * D + c0 + c] = v;
  }
  __syncthreads();
#pragma unroll
  for (int i = 0; i < 16; ++i) {
    int r = rb + i * 4;
    Wt[(size_t)(c0 + r) * HZ + r0 + c] = tile[c][r];
  }
}

// ---------------------------------------------------------------------------
// proj: kp/qp[bh][l][z] = sum_d x*W ; kpt/qpt[bh][z][l] in PERMUTED l-order.
// Single-barrier double-buffered pipeline, 16 k-iters.
// ---------------------------------------------------------------------------
__global__ __launch_bounds__(256, 2) void proj_kernel(
    const __bf16* __restrict__ xb, const __bf16* __restrict__ Wkb,
    const __bf16* __restrict__ Wqb,
    __bf16* __restrict__ kp, __bf16* __restrict__ qp,
    __bf16* __restrict__ kpt, __bf16* __restrict__ qpt) {
  const __bf16* __restrict__ Wb = blockIdx.z ? Wqb : Wkb;
  __bf16* __restrict__ outn = blockIdx.z ? qp : kp;
  __bf16* __restrict__ outt = blockIdx.z ? qpt : kpt;
  const int h = blockIdx.x, m0 = blockIdx.y * 64;
  const int tid = threadIdx.x, l = tid & 63, w = tid >> 6;
  const int tx = l & 15, quad = l >> 4;
  __shared__ __align__(16) char sA[2][8192], sB[2][8192];
  StagePiece pc[2];
  pc[0] = piece_of(tid, 0); pc[1] = piece_of(tid, 1);
  const __bf16* __restrict__ Abase = xb + (size_t)m0 * D;
  const __bf16* __restrict__ Bbase = Wb + (size_t)h * 64 * D;

  f32x4 acc[4];
#pragma unroll
  for (int nb = 0; nb < 4; ++nb)
#pragma unroll
    for (int i = 0; i < 4; ++i) acc[nb][i] = 0.f;

  uint4 tvA[2], tvB[2];
#pragma unroll
  for (int it = 0; it < 2; ++it) {
    tvA[it] = *(const uint4*)(Abase + (size_t)pc[it].r * D + pc[it].c * 8);
    tvB[it] = *(const uint4*)(Bbase + (size_t)pc[it].r * D + pc[it].c * 8);
  }
#pragma unroll
  for (int it = 0; it < 2; ++it) {
    *(uint4*)(sA[0] + pc[it].loff) = tvA[it];
    *(uint4*)(sB[0] + pc[it].loff) = tvB[it];
  }
  __syncthreads();

  for (int k = 0; k < 16; ++k) {
    const int cur = k & 1, nxt = cur ^ 1;
    if (k < 15) {
      const int k0 = (k + 1) * 64;
#pragma unroll
      for (int it = 0; it < 2; ++it) {
        tvA[it] = *(const uint4*)(Abase + (size_t)pc[it].r * D + k0 + pc[it].c * 8);
        tvB[it] = *(const uint4*)(Bbase + (size_t)pc[it].r * D + k0 + pc[it].c * 8);
      }
    }
#pragma unroll
    for (int t = 0; t < 2; ++t) {
      bf16x8 a = frag(sA[cur], w, t, l);
#pragma unroll
      for (int nb = 0; nb < 4; ++nb)
        acc[nb] = __builtin_amdgcn_mfma_f32_16x16x32_bf16(
            a, frag(sB[cur], nb, t, l), acc[nb], 0, 0, 0);
    }
    if (k < 15) {
#pragma unroll
      for (int it = 0; it < 2; ++it) {
        *(uint4*)(sA[nxt] + pc[it].loff) = tvA[it];
        *(uint4*)(sB[nxt] + pc[it].loff) = tvB[it];
      }
    }
    __syncthreads();
  }

  const size_t bh = (size_t)(m0 >> 11) * H + h;
  const int l0 = (m0 & (L - 1)) + 16 * w + 4 * quad;
  const int l0p = (m0 & (L - 1)) + 16 * w + ((quad & 1) << 3) + ((quad >> 1) << 2);
#pragma unroll
  for (int nb = 0; nb < 4; ++nb) {
    const int z = nb * 16 + tx;
    union { __bf16 hh[4]; uint2 u; } pk;
#pragma unroll
    for (int r = 0; r < 4; ++r) pk.hh[r] = (__bf16)acc[nb][r];
    *(uint2*)(outt + (bh * Z + z) * L + l0p) = pk.u;
#pragma unroll
    for (int r = 0; r < 4; ++r) outn[(bh * L + l0 + r) * Z + z] = pk.hh[r];
  }
}

// ---------------------------------------------------------------------------
// grad kernel: 32x32x16 MFMA, 1 q-tile (32 rows) per wave; av register-
// double-buffered direct global fragments; T tile via single-barrier
// double-buffered LDS. Index math identical to round 4 (validated).
// ---------------------------------------------------------------------------
template<int MODE>
__global__ __launch_bounds__(256, 2) void grad_kernel(
    const __bf16* __restrict__ Rg, const __bf16* __restrict__ Sg,
    const __bf16* __restrict__ Tg, const float* __restrict__ beta_p,
    float* __restrict__ lse, __bf16* __restrict__ Gout) {
  const int bid = blockIdx.x;
  const int slot = bid >> 3;
  const int bh = (bid & 7) * 4 + (slot >> 4);   // 4 bh per XCD
  const int qt = slot & 15;
  const float beta = beta_p[0];
  const int tid = threadIdx.x, l = tid & 63, w = tid >> 6;
  const int l31 = l & 31, hi = l >> 5;
  const int q0 = qt * 128 + w * 32;
  __shared__ __align__(16) char sT[2][8192];
  StagePiece pc[2];
  pc[0] = piece_of(tid, 0); pc[1] = piece_of(tid, 1);

  // resident operand as 32x32x16 B-fragments: B[n=l31][k=16ks+8hi+j]
  bf16x8 bres[4];
#pragma unroll
  for (int ks = 0; ks < 4; ++ks)
    bres[ks] = *(const bf16x8*)(
        Rg + ((size_t)bh * L + q0 + l31) * Z + ks * 16 + hi * 8);

  f32x16 pv[2];
#pragma unroll
  for (int zt = 0; zt < 2; ++zt)
#pragma unroll
    for (int i = 0; i < 16; ++i) pv[zt][i] = 0.f;
  float li = 0.f;

  const __bf16* __restrict__ Sbase =
      Sg + (size_t)bh * L * Z + (size_t)l31 * Z + hi * 8;
  const __bf16* __restrict__ Tbase = Tg + (size_t)bh * Z * L;

  // prologue: tile 0 into regs + LDS buf0; av tile 0 into avb[0]
  bf16x8 avb[2][8];
  uint4 tv[2];
#pragma unroll
  for (int nt = 0; nt < 2; ++nt)
#pragma unroll
    for (int ks = 0; ks < 4; ++ks)
      avb[0][nt * 4 + ks] =
          *(const bf16x8*)(Sbase + (size_t)(nt * 32) * Z + ks * 16);
#pragma unroll
  for (int it = 0; it < 2; ++it)
    tv[it] = *(const uint4*)(Tbase + (size_t)pc[it].r * L + pc[it].c * 8);
#pragma unroll
  for (int it = 0; it < 2; ++it) *(uint4*)(sT[0] + pc[it].loff) = tv[it];
  __syncthreads();

  for (int kt = 0; kt < 32; ++kt) {
    const int cur = kt & 1, nxt = cur ^ 1;
    if (kt < 31) {
      // prefetch next av fragments + next T tile into regs
#pragma unroll
      for (int nt = 0; nt < 2; ++nt)
#pragma unroll
        for (int ks = 0; ks < 4; ++ks)
          avb[nxt][nt * 4 + ks] = *(const bf16x8*)(
              Sbase + (size_t)((kt + 1) * 64 + nt * 32) * Z + ks * 16);
#pragma unroll
      for (int it = 0; it < 2; ++it)
        tv[it] = *(const uint4*)(
            Tbase + (kt + 1) * 64 + (size_t)pc[it].r * L + pc[it].c * 8);
    }
    // St[c][q] = sum_z streamed[c][z] * resident[q][z]
    f32x16 st[2];
#pragma unroll
    for (int i = 0; i < 16; ++i) { st[0][i] = 0.f; st[1][i] = 0.f; }
#pragma unroll
    for (int ks = 0; ks < 4; ++ks) {
      st[0] = __builtin_amdgcn_mfma_f32_32x32x16_bf16(
          avb[cur][ks], bres[ks], st[0], 0, 0, 0);
      st[1] = __builtin_amdgcn_mfma_f32_32x32x16_bf16(
          avb[cur][4 + ks], bres[ks], st[1], 0, 0, 0);
    }
    // P = exp(beta*St) (fixed max=0), packed as PV A-frags
    uint32_t P32[2][8];
    float lsn = 0.f;
#pragma unroll
    for (int nt = 0; nt < 2; ++nt)
#pragma unroll
      for (int i = 0; i < 8; ++i) {
        float e0 = __expf(beta * st[nt][2 * i]);
        float e1 = __expf(beta * st[nt][2 * i + 1]);
        if (MODE == 0) lsn += e0 + e1;
        union { __bf16 hh[2]; uint32_t u; } pk;
        pk.hh[0] = (__bf16)e0; pk.hh[1] = (__bf16)e1;
        P32[nt][i] = pk.u;
      }
    if (MODE == 0) li += lsn;
    // PV: D[q][z] += P[q][c] * T[c][z]
#pragma unroll
    for (int kc = 0; kc < 4; ++kc) {
      union { uint32_t u[4]; bf16x8 v; } a;
#pragma unroll
      for (int i = 0; i < 4; ++i) a.u[i] = P32[kc >> 1][4 * (kc & 1) + i];
      pv[0] = __builtin_amdgcn_mfma_f32_32x32x16_bf16(
          a.v, rfrag(sT[cur], l31, 2 * kc + hi), pv[0], 0, 0, 0);
      pv[1] = __builtin_amdgcn_mfma_f32_32x32x16_bf16(
          a.v, rfrag(sT[cur], 32 + l31, 2 * kc + hi), pv[1], 0, 0, 0);
    }
    if (kt < 31) {
#pragma unroll
      for (int it = 0; it < 2; ++it) *(uint4*)(sT[nxt] + pc[it].loff) = tv[it];
    }
    __syncthreads();
  }
  if (MODE == 0) li += __shfl_xor(li, 32);   // partner holds the other 32 c's
  const int b = bh >> 4, head = bh & (H - 1);
#pragma unroll
  for (int r = 0; r < 16; ++r) {
    const int qoff = (r & 3) + 8 * (r >> 2) + 4 * hi;   // C-layout row
    float scl = 1.f;
    if (MODE == 0)
      scl = 1.f / __int_as_float(
                __builtin_amdgcn_ds_bpermute(4 * qoff, __float_as_int(li)));
    const size_t orow = ((size_t)b * L + q0 + qoff) * HZ + head * Z;
    Gout[orow + l31]      = (__bf16)(-pv[0][r] * scl);
    Gout[orow + 32 + l31] = (__bf16)(-pv[1][r] * scl);
  }
  if (MODE == 0 && hi == 0)
    lse[(size_t)bh * L + q0 + l31] = __logf(li);
}

// ---------------------------------------------------------------------------
// kpt[row][pos] *= exp(-lse[true_l(pos)])  (in place; pos is l-permuted)
// ---------------------------------------------------------------------------
__global__ __launch_bounds__(256) void kscale_kernel(__bf16* __restrict__ kpt,
                                                     const float* __restrict__ lse) {
  int idx = blockIdx.x * 256 + threadIdx.x;   // 1M 4-el pieces
  int row = idx >> 9;                          // bh*64 + z
  int pos4 = (idx & 511) << 2;
  int bh = row >> 6;
  int lbase = (pos4 & ~15) + (((pos4 >> 2) & 1) << 3) + (((pos4 >> 3) & 1) << 2);
  float4 ls = *(const float4*)(lse + (size_t)bh * L + lbase);
  __bf16* p = kpt + (size_t)row * L + pos4;
  union { __bf16 hh[4]; uint2 u; } v;
  v.u = *(uint2*)p;
  v.hh[0] = (__bf16)((float)v.hh[0] * __expf(-ls.x));
  v.hh[1] = (__bf16)((float)v.hh[1] * __expf(-ls.y));
  v.hh[2] = (__bf16)((float)v.hh[2] * __expf(-ls.z));
  v.hh[3] = (__bf16)((float)v.hh[3] * __expf(-ls.w));
  *(uint2*)p = v.u;
}

// ---------------------------------------------------------------------------
// en[b] = -(1/beta) * sum_{h,q} lse[b,h,q]
// ---------------------------------------------------------------------------
__global__ __launch_bounds__(256) void energy_kernel(
    const float* __restrict__ lse_ws, const float* __restrict__ beta_p,
    float* __restrict__ out) {
  const int b = blockIdx.x;
  const float* p = lse_ws + (size_t)b * H * L;
  float sum = 0.f;
  for (int i = threadIdx.x; i < H * L; i += 256) sum += p[i];
#pragma unroll
  for (int off = 1; off < 64; off <<= 1) sum += __shfl_xor(sum, off, 64);
  __shared__ float wsum[4];
  if ((threadIdx.x & 63) == 0) wsum[threadIdx.x >> 6] = sum;
  __syncthreads();
  if (threadIdx.x == 0)
    out[b] = -(wsum[0] + wsum[1] + wsum[2] + wsum[3]) / beta_p[0];
}

// ---------------------------------------------------------------------------
// gx[m][d] = sum_hz Gkp[m][hz]*Wk[hz][d] + Gqp[m][hz]*Wq[hz][d]
// Flattened 32-iter single-barrier double-buffered pipeline.
// ---------------------------------------------------------------------------
__global__ __launch_bounds__(256, 2) void gx_kernel(
    const __bf16* __restrict__ Gkp, const __bf16* __restrict__ Gqp,
    const __bf16* __restrict__ Wkt, const __bf16* __restrict__ Wqt,
    float* __restrict__ gx) {
  const int n0 = blockIdx.x * 64, m0 = blockIdx.y * 64;
  const int tid = threadIdx.x, l = tid & 63, w = tid >> 6;
  const int tx = l & 15, quad = l >> 4;
  __shared__ __align__(16) char sA[2][8192], sB[2][8192];
  StagePiece pc[2];
  pc[0] = piece_of(tid, 0); pc[1] = piece_of(tid, 1);
  const __bf16* __restrict__ Asrc[2] = {Gkp, Gqp};
  const __bf16* __restrict__ Bsrc[2] = {Wkt, Wqt};

  f32x4 acc[4];
#pragma unroll
  for (int nb = 0; nb < 4; ++nb)
#pragma unroll
    for (int i = 0; i < 4; ++i) acc[nb][i] = 0.f;

  uint4 tvA[2], tvB[2];
#pragma unroll
  for (int it = 0; it < 2; ++it) {
    tvA[it] = *(const uint4*)(Asrc[0] + (size_t)(m0 + pc[it].r) * HZ + pc[it].c * 8);
    tvB[it] = *(const uint4*)(Bsrc[0] + (size_t)(n0 + pc[it].r) * HZ + pc[it].c * 8);
  }
#pragma unroll
  for (int it = 0; it < 2; ++it) {
    *(uint4*)(sA[0] + pc[it].loff) = tvA[it];
    *(uint4*)(sB[0] + pc[it].loff) = tvB[it];
  }
  __syncthreads();

  for (int kk = 0; kk < 32; ++kk) {
    const int cur = kk & 1, nxt = cur ^ 1;
    if (kk < 31) {
      const int ns = (kk + 1) >> 4, k0 = ((kk + 1) & 15) * 64;
#pragma unroll
      for (int it = 0; it < 2; ++it) {
        tvA[it] = *(const uint4*)(Asrc[ns] + (size_t)(m0 + pc[it].r) * HZ + k0 + pc[it].c * 8);
        tvB[it] = *(const uint4*)(Bsrc[ns] + (size_t)(n0 + pc[it].r) * HZ + k0 + pc[it].c * 8);
      }
    }
#pragma unroll
    for (int t = 0; t < 2; ++t) {
      bf16x8 a = frag(sA[cur], w, t, l);
#pragma unroll
      for (int nb = 0; nb < 4; ++nb)
        acc[nb] = __builtin_amdgcn_mfma_f32_16x16x32_bf16(
            a, frag(sB[cur], nb, t, l), acc[nb], 0, 0, 0);
    }
    if (kk < 31) {
#pragma unroll
      for (int it = 0; it < 2; ++it) {
        *(uint4*)(sA[nxt] + pc[it].loff) = tvA[it];
        *(uint4*)(sB[nxt] + pc[it].loff) = tvB[it];
      }
    }
    __syncthreads();
  }
#pragma unroll
  for (int nb = 0; nb < 4; ++nb)
#pragma unroll
    for (int r = 0; r < 4; ++r)
      gx[(size_t)(m0 + 16 * w + 4 * quad + r) * D + n0 + nb * 16 + tx] =
          acc[nb][r];
}

// ---------------------------------------------------------------------------
extern "C" void kernel_launch(void* const* d_in, const int* in_sizes, int n_in,
                              void* d_out, int out_size, void* d_ws, size_t ws_size,
                              hipStream_t stream) {
  const float* x    = (const float*)d_in[0];
  const float* Wq   = (const float*)d_in[1];
  const float* Wk   = (const float*)d_in[2];
  const float* beta = (const float*)d_in[3];
  float* out = (float*)d_out;

  char* ws = (char*)d_ws;
  __bf16* xb  = (__bf16*)(ws);                         // 8 MB
  __bf16* Wkb = (__bf16*)(ws + (8ull  << 20));         // 2 MB
  __bf16* Wqb = (__bf16*)(ws + (10ull << 20));         // 2 MB
  __bf16* Wkt = (__bf16*)(ws + (12ull << 20));         // 2 MB
  __bf16* Wqt = (__bf16*)(ws + (14ull << 20));         // 2 MB
  __bf16* kp  = (__bf16*)(ws + (16ull << 20));         // 8 MB
  __bf16* qp  = (__bf16*)(ws + (24ull << 20));         // 8 MB
  __bf16* kpt = (__bf16*)(ws + (32ull << 20));         // 8 MB (l-permuted)
  __bf16* qpt = (__bf16*)(ws + (40ull << 20));         // 8 MB (l-permuted)
  __bf16* Gkp = (__bf16*)(ws + (48ull << 20));         // 8 MB
  __bf16* Gqp = (__bf16*)(ws + (56ull << 20));         // 8 MB
  float*  lse = (float*)(ws + (64ull << 20));          // 256 KB

  cvt_kernel<<<4096, 256, 0, stream>>>(x, xb, 1048576);
  wt_kernel<<<dim3(16, 16, 2), 256, 0, stream>>>(Wk, Wq, Wkb, Wqb, Wkt, Wqt);
  proj_kernel<<<dim3(16, 64, 2), 256, 0, stream>>>(xb, Wkb, Wqb, kp, qp, kpt, qpt);
  grad_kernel<0><<<512, 256, 0, stream>>>(kp, qp, qpt, beta, lse, Gkp);
  kscale_kernel<<<4096, 256, 0, stream>>>(kpt, lse);
  grad_kernel<1><<<512, 256, 0, stream>>>(qp, kp, kpt, beta, lse, Gqp);
  energy_kernel<<<2, 256, 0, stream>>>(lse, beta, out);
  gx_kernel<<<dim3(16, 64), 256, 0, stream>>>(Gkp, Gqp, Wkt, Wqt, out + 2);
}

// Round 6
// 352.970 us; speedup vs baseline: 1.9693x; 1.9693x over previous
//
#include <hip/hip_runtime.h>

#define L 2048
#define D 1024
#define H 16
#define Z 64
#define HZ 1024

typedef __bf16 bf16x8 __attribute__((ext_vector_type(8)));
typedef float f32x4 __attribute__((ext_vector_type(4)));
typedef float f32x16 __attribute__((ext_vector_type(16)));

// ---------------------------------------------------------------------------
// Async global->LDS DMA, 16B per lane. LDS dest must be wave-uniform base;
// HW writes lane i at base + i*16. (CK-style addrspace cast dance.)
// ---------------------------------------------------------------------------
__device__ __forceinline__ void async_ld16(const void* g, void* l) {
  __builtin_amdgcn_global_load_lds(
      (const __attribute__((address_space(1))) uint32_t*)(uintptr_t)g,
      (__attribute__((address_space(3))) uint32_t*)(uint32_t)(uintptr_t)l,
      16, 0, 0);
}

// ---------------------------------------------------------------------------
// Fragment-ordered tile staging. Tile = NR rows x 64 bf16 cols, NR in {64,128}.
// 1KB region per (16-row group, 32-col half): region = (r>>4)*2 + (cc>>2),
// slot = (r&15) + (cc&3)*16  (cc = 16B chunk index 0..7).
// Wave w stages regions {it*4+w}, lane l at +l*16:
//   r = (region>>1)*16 + (l&15), c8 = (region&1)*4 + (l>>4).
// ---------------------------------------------------------------------------
template<int NPIECE>
__device__ __forceinline__ void stage_async(const __bf16* __restrict__ g,
                                            int gstride, char* lds, int tid) {
  const int l = tid & 63, w = tid >> 6;
#pragma unroll
  for (int it = 0; it < NPIECE; ++it) {
    const int region = it * 4 + w;
    const int r = ((region >> 1) << 4) + (l & 15);
    const int c = ((region & 1) << 2) + (l >> 4);
    async_ld16(g + (size_t)r * gstride + c * 8, lds + (region << 10));
  }
}

__device__ __forceinline__ bf16x8 rfrag(const char* lds, int row, int cc) {
  const int region = ((row >> 4) << 1) + (cc >> 2);
  const int slot = (row & 15) + ((cc & 3) << 4);
  return *(const bf16x8*)(lds + region * 1024 + slot * 16);
}

// ---------------------------------------------------------------------------
// fp32 -> bf16 flat convert (n4 = n/4)
// ---------------------------------------------------------------------------
__global__ __launch_bounds__(256) void cvt_kernel(const float* __restrict__ s,
                                                  __bf16* __restrict__ d, int n4) {
  int i = blockIdx.x * 256 + threadIdx.x;
  if (i < n4) {
    float4 v = ((const float4*)s)[i];
    union { __bf16 h[4]; uint2 u; } o;
    o.h[0] = (__bf16)v.x; o.h[1] = (__bf16)v.y;
    o.h[2] = (__bf16)v.z; o.h[3] = (__bf16)v.w;
    ((uint2*)d)[i] = o.u;
  }
}

// ---------------------------------------------------------------------------
// W (fp32) -> Wb (bf16 straight) + Wt (bf16 transposed)
// ---------------------------------------------------------------------------
__global__ __launch_bounds__(256) void wt_kernel(
    const float* __restrict__ Wk, const float* __restrict__ Wq,
    __bf16* __restrict__ Wkb, __bf16* __restrict__ Wqb,
    __bf16* __restrict__ Wkt, __bf16* __restrict__ Wqt) {
  const float* W = blockIdx.z ? Wq : Wk;
  __bf16* Wb = blockIdx.z ? Wqb : Wkb;
  __bf16* Wt = blockIdx.z ? Wqt : Wkt;
  __shared__ __bf16 tile[64][65];
  const int r0 = blockIdx.y * 64, c0 = blockIdx.x * 64;
  const int c = threadIdx.x & 63, rb = threadIdx.x >> 6;
#pragma unroll
  for (int i = 0; i < 16; ++i) {
    int r = rb + i * 4;
    __bf16 v = (__bf16)W[(size_t)(r0 + r) * D + c0 + c];
    tile[r][c] = v;
    Wb[(size_t)(r0 + r) * D + c0 + c] = v;
  }
  __syncthreads();
#pragma unroll
  for (int i = 0; i < 16; ++i) {
    int r = rb + i * 4;
    Wt[(size_t)(c0 + r) * HZ + r0 + c] = tile[c][r];
  }
}

// l-permutation for the transposed kp/qp buffers: within each 16-l group,
// 4-el pieces stored in order [0-3, 8-11, 4-7, 12-15].
__device__ __forceinline__ int lperm(int mg) {
  const int off = mg & 15;
  return (mg & ~15) | (((off >> 2) & 1) << 3) | (((off >> 3) & 1) << 2);
}

// ---------------------------------------------------------------------------
// proj: kp/qp[bh][l][z] = sum_d x*W; kpt/qpt[bh][z][l] (l-permuted).
// 128x128 tile, 4 waves x 64x64 quadrant, 32x32x16 MFMA, BK=64,
// async-DMA double-buffered LDS, single barrier per K-iter.
// grid (8 n-tiles(2 heads), 32 m-tiles, 2 {k,q})
// ---------------------------------------------------------------------------
__global__ __launch_bounds__(256, 2) void proj_kernel(
    const __bf16* __restrict__ xb, const __bf16* __restrict__ Wkb,
    const __bf16* __restrict__ Wqb,
    __bf16* __restrict__ kp, __bf16* __restrict__ qp,
    __bf16* __restrict__ kpt, __bf16* __restrict__ qpt) {
  const __bf16* __restrict__ Wb = blockIdx.z ? Wqb : Wkb;
  __bf16* __restrict__ outn = blockIdx.z ? qp : kp;
  __bf16* __restrict__ outt = blockIdx.z ? qpt : kpt;
  const int n0 = blockIdx.x * 128, m0 = blockIdx.y * 128;
  const int tid = threadIdx.x, l = tid & 63, w = tid >> 6;
  const int l31 = l & 31, hi = l >> 5;
  const int mh = w >> 1, nh = w & 1;
  __shared__ __align__(16) char sA[2][16384], sB[2][16384];

  f32x16 acc[2][2];
#pragma unroll
  for (int mi = 0; mi < 2; ++mi)
#pragma unroll
    for (int ni = 0; ni < 2; ++ni)
#pragma unroll
      for (int i = 0; i < 16; ++i) acc[mi][ni][i] = 0.f;

  const __bf16* __restrict__ Abase = xb + (size_t)m0 * D;
  const __bf16* __restrict__ Bbase = Wb + (size_t)n0 * D;
  stage_async<4>(Abase, D, sA[0], tid);
  stage_async<4>(Bbase, D, sB[0], tid);
  __syncthreads();

  for (int k = 0; k < 16; ++k) {
    const int cur = k & 1, nxt = cur ^ 1;
    if (k < 15) {
      stage_async<4>(Abase + (k + 1) * 64, D, sA[nxt], tid);
      stage_async<4>(Bbase + (k + 1) * 64, D, sB[nxt], tid);
    }
#pragma unroll
    for (int ks = 0; ks < 4; ++ks) {
      bf16x8 am[2], bn[2];
#pragma unroll
      for (int mi = 0; mi < 2; ++mi)
        am[mi] = rfrag(sA[cur], mh * 64 + mi * 32 + l31, 2 * ks + hi);
#pragma unroll
      for (int ni = 0; ni < 2; ++ni)
        bn[ni] = rfrag(sB[cur], nh * 64 + ni * 32 + l31, 2 * ks + hi);
#pragma unroll
      for (int mi = 0; mi < 2; ++mi)
#pragma unroll
        for (int ni = 0; ni < 2; ++ni)
          acc[mi][ni] = __builtin_amdgcn_mfma_f32_32x32x16_bf16(
              am[mi], bn[ni], acc[mi][ni], 0, 0, 0);
    }
    __syncthreads();
  }

  const int b = m0 >> 11;
  const int h = (n0 >> 6) + nh;
  const size_t bh = (size_t)b * H + h;
#pragma unroll
  for (int mi = 0; mi < 2; ++mi)
#pragma unroll
    for (int ni = 0; ni < 2; ++ni) {
      const int z = ni * 32 + l31;
#pragma unroll
      for (int rg = 0; rg < 4; ++rg) {
        const int mloc = mh * 64 + mi * 32 + 8 * rg + 4 * hi;
        const int mg = (m0 & (L - 1)) + mloc;
        union { __bf16 hh[4]; uint2 u; } pk;
#pragma unroll
        for (int j = 0; j < 4; ++j) {
          pk.hh[j] = (__bf16)acc[mi][ni][4 * rg + j];
          outn[(bh * L + mg + j) * Z + z] = pk.hh[j];
        }
        *(uint2*)(outt + (bh * Z + z) * L + lperm(mg)) = pk.u;
      }
    }
}

// ---------------------------------------------------------------------------
// grad kernel: 32x32x16 MFMA, 1 q-tile (32 rows) per wave; av fragments
// direct from global (single buffer, reloaded after St consumes them);
// T tile async-DMA into double-buffered LDS; ONE barrier per k-tile.
// MODE 0: Gkp[q][z] = -(1/li_q) sum_c exp(b*S[q][c]) * qp[c][z]; lse=log(li)
// MODE 1: Gqp[kq][z] = -sum_q exp(b*S[q][kq]) * kpw[q][z]  (kpw pre-scaled)
// grid = 512 blocks, XCD-swizzled (4 bh per XCD).
// ---------------------------------------------------------------------------
template<int MODE>
__global__ __launch_bounds__(256, 2) void grad_kernel(
    const __bf16* __restrict__ Rg, const __bf16* __restrict__ Sg,
    const __bf16* __restrict__ Tg, const float* __restrict__ beta_p,
    float* __restrict__ lse, __bf16* __restrict__ Gout) {
  const int bid = blockIdx.x;
  const int slot = bid >> 3;
  const int bh = (bid & 7) * 4 + (slot >> 4);
  const int qt = slot & 15;
  const float beta = beta_p[0];
  const int tid = threadIdx.x, l = tid & 63, w = tid >> 6;
  const int l31 = l & 31, hi = l >> 5;
  const int q0 = qt * 128 + w * 32;
  __shared__ __align__(16) char sT[2][8192];

  // resident operand as 32x32x16 B-fragments: B[n=l31][k=16ks+8hi+j]
  bf16x8 bres[4];
#pragma unroll
  for (int ks = 0; ks < 4; ++ks)
    bres[ks] = *(const bf16x8*)(
        Rg + ((size_t)bh * L + q0 + l31) * Z + ks * 16 + hi * 8);

  f32x16 pv[2];
#pragma unroll
  for (int zt = 0; zt < 2; ++zt)
#pragma unroll
    for (int i = 0; i < 16; ++i) pv[zt][i] = 0.f;
  float li = 0.f;

  const __bf16* __restrict__ Sbase =
      Sg + (size_t)bh * L * Z + (size_t)l31 * Z + hi * 8;
  const __bf16* __restrict__ Tbase = Tg + (size_t)bh * Z * L;

  // prologue: async T0 -> sT[0]; av fragments for kt=0
  stage_async<2>(Tbase, L, sT[0], tid);
  bf16x8 av[8];
#pragma unroll
  for (int nt = 0; nt < 2; ++nt)
#pragma unroll
    for (int ks = 0; ks < 4; ++ks)
      av[nt * 4 + ks] = *(const bf16x8*)(Sbase + (size_t)(nt * 32) * Z + ks * 16);
  __syncthreads();

  for (int kt = 0; kt < 32; ++kt) {
    const int cur = kt & 1, nxt = cur ^ 1;
    if (kt < 31) stage_async<2>(Tbase + (kt + 1) * 64, L, sT[nxt], tid);
    // St[c][q] = sum_z streamed[c][z] * resident[q][z]
    f32x16 st[2];
#pragma unroll
    for (int i = 0; i < 16; ++i) { st[0][i] = 0.f; st[1][i] = 0.f; }
#pragma unroll
    for (int ks = 0; ks < 4; ++ks) {
      st[0] = __builtin_amdgcn_mfma_f32_32x32x16_bf16(av[ks], bres[ks], st[0], 0, 0, 0);
      st[1] = __builtin_amdgcn_mfma_f32_32x32x16_bf16(av[4 + ks], bres[ks], st[1], 0, 0, 0);
    }
    // reload av for kt+1 now that St consumed them (latency hidden by exp+PV)
    if (kt < 31) {
#pragma unroll
      for (int nt = 0; nt < 2; ++nt)
#pragma unroll
        for (int ks = 0; ks < 4; ++ks)
          av[nt * 4 + ks] = *(const bf16x8*)(
              Sbase + (size_t)((kt + 1) * 64 + nt * 32) * Z + ks * 16);
    }
    // P = exp(beta*St) (fixed max=0), packed as PV A-frags
    uint32_t P32[2][8];
    float lsn = 0.f;
#pragma unroll
    for (int nt = 0; nt < 2; ++nt)
#pragma unroll
      for (int i = 0; i < 8; ++i) {
        float e0 = __expf(beta * st[nt][2 * i]);
        float e1 = __expf(beta * st[nt][2 * i + 1]);
        if (MODE == 0) lsn += e0 + e1;
        union { __bf16 hh[2]; uint32_t u; } pk;
        pk.hh[0] = (__bf16)e0; pk.hh[1] = (__bf16)e1;
        P32[nt][i] = pk.u;
      }
    if (MODE == 0) li += lsn;
    // PV: D[q][z] += P[q][c] * T[c][z]
#pragma unroll
    for (int kc = 0; kc < 4; ++kc) {
      union { uint32_t u[4]; bf16x8 v; } a;
#pragma unroll
      for (int i = 0; i < 4; ++i) a.u[i] = P32[kc >> 1][4 * (kc & 1) + i];
      pv[0] = __builtin_amdgcn_mfma_f32_32x32x16_bf16(
          a.v, rfrag(sT[cur], l31, 2 * kc + hi), pv[0], 0, 0, 0);
      pv[1] = __builtin_amdgcn_mfma_f32_32x32x16_bf16(
          a.v, rfrag(sT[cur], 32 + l31, 2 * kc + hi), pv[1], 0, 0, 0);
    }
    __syncthreads();
  }
  if (MODE == 0) li += __shfl_xor(li, 32);
  const int b = bh >> 4, head = bh & (H - 1);
#pragma unroll
  for (int r = 0; r < 16; ++r) {
    const int qoff = (r & 3) + 8 * (r >> 2) + 4 * hi;   // C-layout row
    float scl = 1.f;
    if (MODE == 0)
      scl = 1.f / __int_as_float(
                __builtin_amdgcn_ds_bpermute(4 * qoff, __float_as_int(li)));
    const size_t orow = ((size_t)b * L + q0 + qoff) * HZ + head * Z;
    Gout[orow + l31]      = (__bf16)(-pv[0][r] * scl);
    Gout[orow + 32 + l31] = (__bf16)(-pv[1][r] * scl);
  }
  if (MODE == 0 && hi == 0)
    lse[(size_t)bh * L + q0 + l31] = __logf(li);
}

// ---------------------------------------------------------------------------
// kpt[row][pos] *= exp(-lse[true_l(pos)])  (in place; pos is l-permuted)
// ---------------------------------------------------------------------------
__global__ __launch_bounds__(256) void kscale_kernel(__bf16* __restrict__ kpt,
                                                     const float* __restrict__ lse) {
  int idx = blockIdx.x * 256 + threadIdx.x;
  int row = idx >> 9;                          // bh*64 + z
  int pos4 = (idx & 511) << 2;
  int bh = row >> 6;
  int lbase = (pos4 & ~15) + (((pos4 >> 2) & 1) << 3) + (((pos4 >> 3) & 1) << 2);
  float4 ls = *(const float4*)(lse + (size_t)bh * L + lbase);
  __bf16* p = kpt + (size_t)row * L + pos4;
  union { __bf16 hh[4]; uint2 u; } v;
  v.u = *(uint2*)p;
  v.hh[0] = (__bf16)((float)v.hh[0] * __expf(-ls.x));
  v.hh[1] = (__bf16)((float)v.hh[1] * __expf(-ls.y));
  v.hh[2] = (__bf16)((float)v.hh[2] * __expf(-ls.z));
  v.hh[3] = (__bf16)((float)v.hh[3] * __expf(-ls.w));
  *(uint2*)p = v.u;
}

// ---------------------------------------------------------------------------
// en[b] = -(1/beta) * sum_{h,q} lse[b,h,q]
// ---------------------------------------------------------------------------
__global__ __launch_bounds__(256) void energy_kernel(
    const float* __restrict__ lse_ws, const float* __restrict__ beta_p,
    float* __restrict__ out) {
  const int b = blockIdx.x;
  const float* p = lse_ws + (size_t)b * H * L;
  float sum = 0.f;
  for (int i = threadIdx.x; i < H * L; i += 256) sum += p[i];
#pragma unroll
  for (int off = 1; off < 64; off <<= 1) sum += __shfl_xor(sum, off, 64);
  __shared__ float wsum[4];
  if ((threadIdx.x & 63) == 0) wsum[threadIdx.x >> 6] = sum;
  __syncthreads();
  if (threadIdx.x == 0)
    out[b] = -(wsum[0] + wsum[1] + wsum[2] + wsum[3]) / beta_p[0];
}

// ---------------------------------------------------------------------------
// gx[m][d] = sum_hz Gkp[m][hz]*Wk[hz][d] + Gqp[m][hz]*Wq[hz][d]
// 128x128 tile, K=2048 (two stacked 1024 sources), async double-buffered.
// grid (8 d-tiles, 32 m-tiles)
// ---------------------------------------------------------------------------
__global__ __launch_bounds__(256, 2) void gx_kernel(
    const __bf16* __restrict__ Gkp, const __bf16* __restrict__ Gqp,
    const __bf16* __restrict__ Wkt, const __bf16* __restrict__ Wqt,
    float* __restrict__ gx) {
  const int n0 = blockIdx.x * 128, m0 = blockIdx.y * 128;
  const int tid = threadIdx.x, l = tid & 63, w = tid >> 6;
  const int l31 = l & 31, hi = l >> 5;
  const int mh = w >> 1, nh = w & 1;
  __shared__ __align__(16) char sA[2][16384], sB[2][16384];

  f32x16 acc[2][2];
#pragma unroll
  for (int mi = 0; mi < 2; ++mi)
#pragma unroll
    for (int ni = 0; ni < 2; ++ni)
#pragma unroll
      for (int i = 0; i < 16; ++i) acc[mi][ni][i] = 0.f;

  stage_async<4>(Gkp + (size_t)m0 * HZ, HZ, sA[0], tid);
  stage_async<4>(Wkt + (size_t)n0 * HZ, HZ, sB[0], tid);
  __syncthreads();

  for (int kk = 0; kk < 32; ++kk) {
    const int cur = kk & 1, nxt = cur ^ 1;
    if (kk < 31) {
      const int kn = kk + 1;
      const __bf16* __restrict__ An = (kn < 16 ? Gkp : Gqp);
      const __bf16* __restrict__ Bn = (kn < 16 ? Wkt : Wqt);
      const int k0 = (kn & 15) * 64;
      stage_async<4>(An + (size_t)m0 * HZ + k0, HZ, sA[nxt], tid);
      stage_async<4>(Bn + (size_t)n0 * HZ + k0, HZ, sB[nxt], tid);
    }
#pragma unroll
    for (int ks = 0; ks < 4; ++ks) {
      bf16x8 am[2], bn[2];
#pragma unroll
      for (int mi = 0; mi < 2; ++mi)
        am[mi] = rfrag(sA[cur], mh * 64 + mi * 32 + l31, 2 * ks + hi);
#pragma unroll
      for (int ni = 0; ni < 2; ++ni)
        bn[ni] = rfrag(sB[cur], nh * 64 + ni * 32 + l31, 2 * ks + hi);
#pragma unroll
      for (int mi = 0; mi < 2; ++mi)
#pragma unroll
        for (int ni = 0; ni < 2; ++ni)
          acc[mi][ni] = __builtin_amdgcn_mfma_f32_32x32x16_bf16(
              am[mi], bn[ni], acc[mi][ni], 0, 0, 0);
    }
    __syncthreads();
  }
#pragma unroll
  for (int mi = 0; mi < 2; ++mi)
#pragma unroll
    for (int ni = 0; ni < 2; ++ni) {
      const int n = n0 + nh * 64 + ni * 32 + l31;
#pragma unroll
      for (int r = 0; r < 16; ++r) {
        const int m = m0 + mh * 64 + mi * 32 + (r & 3) + 8 * (r >> 2) + 4 * hi;
        gx[(size_t)m * D + n] = acc[mi][ni][r];
      }
    }
}

// ---------------------------------------------------------------------------
extern "C" void kernel_launch(void* const* d_in, const int* in_sizes, int n_in,
                              void* d_out, int out_size, void* d_ws, size_t ws_size,
                              hipStream_t stream) {
  const float* x    = (const float*)d_in[0];
  const float* Wq   = (const float*)d_in[1];
  const float* Wk   = (const float*)d_in[2];
  const float* beta = (const float*)d_in[3];
  float* out = (float*)d_out;

  char* ws = (char*)d_ws;
  __bf16* xb  = (__bf16*)(ws);                         // 8 MB
  __bf16* Wkb = (__bf16*)(ws + (8ull  << 20));         // 2 MB
  __bf16* Wqb = (__bf16*)(ws + (10ull << 20));         // 2 MB
  __bf16* Wkt = (__bf16*)(ws + (12ull << 20));         // 2 MB
  __bf16* Wqt = (__bf16*)(ws + (14ull << 20));         // 2 MB
  __bf16* kp  = (__bf16*)(ws + (16ull << 20));         // 8 MB
  __bf16* qp  = (__bf16*)(ws + (24ull << 20));         // 8 MB
  __bf16* kpt = (__bf16*)(ws + (32ull << 20));         // 8 MB (l-permuted)
  __bf16* qpt = (__bf16*)(ws + (40ull << 20));         // 8 MB (l-permuted)
  __bf16* Gkp = (__bf16*)(ws + (48ull << 20));         // 8 MB
  __bf16* Gqp = (__bf16*)(ws + (56ull << 20));         // 8 MB
  float*  lse = (float*)(ws + (64ull << 20));          // 256 KB

  cvt_kernel<<<4096, 256, 0, stream>>>(x, xb, 1048576);
  wt_kernel<<<dim3(16, 16, 2), 256, 0, stream>>>(Wk, Wq, Wkb, Wqb, Wkt, Wqt);
  proj_kernel<<<dim3(8, 32, 2), 256, 0, stream>>>(xb, Wkb, Wqb, kp, qp, kpt, qpt);
  grad_kernel<0><<<512, 256, 0, stream>>>(kp, qp, qpt, beta, lse, Gkp);
  kscale_kernel<<<4096, 256, 0, stream>>>(kpt, lse);
  grad_kernel<1><<<512, 256, 0, stream>>>(qp, kp, kpt, beta, lse, Gqp);
  energy_kernel<<<2, 256, 0, stream>>>(lse, beta, out);
  gx_kernel<<<dim3(8, 32), 256, 0, stream>>>(Gkp, Gqp, Wkt, Wqt, out + 2);
}

// Round 7
// 349.795 us; speedup vs baseline: 1.9872x; 1.0091x over previous
//
#include <hip/hip_runtime.h>
#include <math.h>

#define L 2048
#define D 1024
#define H 16
#define Z 64
#define HZ 1024

typedef __bf16 bf16x8 __attribute__((ext_vector_type(8)));
typedef float f32x4 __attribute__((ext_vector_type(4)));
typedef float f32x16 __attribute__((ext_vector_type(16)));

#if __has_builtin(__builtin_amdgcn_exp2f)
#define EXP2(x) __builtin_amdgcn_exp2f(x)
#else
#define EXP2(x) exp2f(x)
#endif

// ---------------------------------------------------------------------------
// Async global->LDS DMA, 16B per lane (lane i lands at base + i*16).
// ---------------------------------------------------------------------------
__device__ __forceinline__ void async_ld16(const void* g, void* l) {
  __builtin_amdgcn_global_load_lds(
      (const __attribute__((address_space(1))) uint32_t*)(uintptr_t)g,
      (__attribute__((address_space(3))) uint32_t*)(uint32_t)(uintptr_t)l,
      16, 0, 0);
}

// ---------------------------------------------------------------------------
// Fragment-ordered tile staging. 1KB region per (16-row group, 32-col half):
// region = (r>>4)*2 + (cc>>2), slot = (r&15) + (cc&3)*16  (cc = 16B chunk).
// ---------------------------------------------------------------------------
template<int NPIECE>
__device__ __forceinline__ void stage_async(const __bf16* __restrict__ g,
                                            int gstride, char* lds, int tid) {
  const int l = tid & 63, w = tid >> 6;
#pragma unroll
  for (int it = 0; it < NPIECE; ++it) {
    const int region = it * 4 + w;
    const int r = ((region >> 1) << 4) + (l & 15);
    const int c = ((region & 1) << 2) + (l >> 4);
    async_ld16(g + (size_t)r * gstride + c * 8, lds + (region << 10));
  }
}

__device__ __forceinline__ bf16x8 rfrag(const char* lds, int row, int cc) {
  const int region = ((row >> 4) << 1) + (cc >> 2);
  const int slot = (row & 15) + ((cc & 3) << 4);
  return *(const bf16x8*)(lds + region * 1024 + slot * 16);
}

// ---------------------------------------------------------------------------
// fp32 -> bf16 flat convert (n4 = n/4)
// ---------------------------------------------------------------------------
__global__ __launch_bounds__(256) void cvt_kernel(const float* __restrict__ s,
                                                  __bf16* __restrict__ d, int n4) {
  int i = blockIdx.x * 256 + threadIdx.x;
  if (i < n4) {
    float4 v = ((const float4*)s)[i];
    union { __bf16 h[4]; uint2 u; } o;
    o.h[0] = (__bf16)v.x; o.h[1] = (__bf16)v.y;
    o.h[2] = (__bf16)v.z; o.h[3] = (__bf16)v.w;
    ((uint2*)d)[i] = o.u;
  }
}

// ---------------------------------------------------------------------------
// W (fp32) -> Wb (bf16 straight) + Wt (bf16 transposed)
// ---------------------------------------------------------------------------
__global__ __launch_bounds__(256) void wt_kernel(
    const float* __restrict__ Wk, const float* __restrict__ Wq,
    __bf16* __restrict__ Wkb, __bf16* __restrict__ Wqb,
    __bf16* __restrict__ Wkt, __bf16* __restrict__ Wqt) {
  const float* W = blockIdx.z ? Wq : Wk;
  __bf16* Wb = blockIdx.z ? Wqb : Wkb;
  __bf16* Wt = blockIdx.z ? Wqt : Wkt;
  __shared__ __bf16 tile[64][65];
  const int r0 = blockIdx.y * 64, c0 = blockIdx.x * 64;
  const int c = threadIdx.x & 63, rb = threadIdx.x >> 6;
#pragma unroll
  for (int i = 0; i < 16; ++i) {
    int r = rb + i * 4;
    __bf16 v = (__bf16)W[(size_t)(r0 + r) * D + c0 + c];
    tile[r][c] = v;
    Wb[(size_t)(r0 + r) * D + c0 + c] = v;
  }
  __syncthreads();
#pragma unroll
  for (int i = 0; i < 16; ++i) {
    int r = rb + i * 4;
    Wt[(size_t)(c0 + r) * HZ + r0 + c] = tile[c][r];
  }
}

// l-permutation for the transposed kp/qp buffers: within each 16-l group,
// 4-el pieces stored in order [0-3, 8-11, 4-7, 12-15].
__device__ __forceinline__ int lperm(int mg) {
  const int off = mg & 15;
  return (mg & ~15) | (((off >> 2) & 1) << 3) | (((off >> 3) & 1) << 2);
}

// ---------------------------------------------------------------------------
// proj: kp/qp[bh][l][z] = SCALE * sum_d x*W   (SCALE = sqrt(beta*log2e), so
//       S-MFMAs in grad produce log2-domain scores directly);
// kpt/qpt[bh][z][l] = UNSCALED (l-permuted) -> PV operands.
// 128x128 tile, 4 waves x 64x64 quadrant, 32x32x16 MFMA, BK=64,
// async-DMA double-buffered LDS, single barrier per K-iter.
// ---------------------------------------------------------------------------
__global__ __launch_bounds__(256, 2) void proj_kernel(
    const __bf16* __restrict__ xb, const __bf16* __restrict__ Wkb,
    const __bf16* __restrict__ Wqb, const float* __restrict__ beta_p,
    __bf16* __restrict__ kp, __bf16* __restrict__ qp,
    __bf16* __restrict__ kpt, __bf16* __restrict__ qpt) {
  const __bf16* __restrict__ Wb = blockIdx.z ? Wqb : Wkb;
  __bf16* __restrict__ outn = blockIdx.z ? qp : kp;
  __bf16* __restrict__ outt = blockIdx.z ? qpt : kpt;
  const int n0 = blockIdx.x * 128, m0 = blockIdx.y * 128;
  const int tid = threadIdx.x, l = tid & 63, w = tid >> 6;
  const int l31 = l & 31, hi = l >> 5;
  const int mh = w >> 1, nh = w & 1;
  const float ab = beta_p[0] * 1.44269504f;
  const float ssc = sqrtf(fabsf(ab));
  const float sc = blockIdx.z ? ssc : ((ab < 0.f) ? -ssc : ssc);
  __shared__ __align__(16) char sA[2][16384], sB[2][16384];

  f32x16 acc[2][2];
#pragma unroll
  for (int mi = 0; mi < 2; ++mi)
#pragma unroll
    for (int ni = 0; ni < 2; ++ni)
#pragma unroll
      for (int i = 0; i < 16; ++i) acc[mi][ni][i] = 0.f;

  const __bf16* __restrict__ Abase = xb + (size_t)m0 * D;
  const __bf16* __restrict__ Bbase = Wb + (size_t)n0 * D;
  stage_async<4>(Abase, D, sA[0], tid);
  stage_async<4>(Bbase, D, sB[0], tid);
  __syncthreads();

  for (int k = 0; k < 16; ++k) {
    const int cur = k & 1, nxt = cur ^ 1;
    if (k < 15) {
      stage_async<4>(Abase + (k + 1) * 64, D, sA[nxt], tid);
      stage_async<4>(Bbase + (k + 1) * 64, D, sB[nxt], tid);
    }
#pragma unroll
    for (int ks = 0; ks < 4; ++ks) {
      bf16x8 am[2], bn[2];
#pragma unroll
      for (int mi = 0; mi < 2; ++mi)
        am[mi] = rfrag(sA[cur], mh * 64 + mi * 32 + l31, 2 * ks + hi);
#pragma unroll
      for (int ni = 0; ni < 2; ++ni)
        bn[ni] = rfrag(sB[cur], nh * 64 + ni * 32 + l31, 2 * ks + hi);
#pragma unroll
      for (int mi = 0; mi < 2; ++mi)
#pragma unroll
        for (int ni = 0; ni < 2; ++ni)
          acc[mi][ni] = __builtin_amdgcn_mfma_f32_32x32x16_bf16(
              am[mi], bn[ni], acc[mi][ni], 0, 0, 0);
    }
    __syncthreads();
  }

  const int b = m0 >> 11;
  const int h = (n0 >> 6) + nh;
  const size_t bh = (size_t)b * H + h;
#pragma unroll
  for (int mi = 0; mi < 2; ++mi)
#pragma unroll
    for (int ni = 0; ni < 2; ++ni) {
      const int z = ni * 32 + l31;
#pragma unroll
      for (int rg = 0; rg < 4; ++rg) {
        const int mloc = mh * 64 + mi * 32 + 8 * rg + 4 * hi;
        const int mg = (m0 & (L - 1)) + mloc;
        union { __bf16 hh[4]; uint2 u; } pk;
#pragma unroll
        for (int j = 0; j < 4; ++j) {
          const float v = acc[mi][ni][4 * rg + j];
          pk.hh[j] = (__bf16)v;                                 // unscaled -> T
          outn[(bh * L + mg + j) * Z + z] = (__bf16)(v * sc);   // scaled -> S ops
        }
        *(uint2*)(outt + (bh * Z + z) * L + lperm(mg)) = pk.u;
      }
    }
}

// ---------------------------------------------------------------------------
// grad kernel: 32x32x16 MFMA, 1 q-tile (32 rows) per wave; av fragments
// direct from global (reloaded after St consumes them); T tile async-DMA
// double-buffered LDS; PV B-frags prefetched at iteration top; one barrier.
// Scores come out of the S-MFMA already in log2-domain (inputs pre-scaled).
// MODE 0: Gkp[q][z] = -(1/li_q) sum_c 2^S[q][c] * qp[c][z]; lse=ln(li)
// MODE 1: Gqp[kq][z] = -sum_q 2^S[q][kq] * kpw[q][z]  (kpw pre-scaled)
// ---------------------------------------------------------------------------
template<int MODE>
__global__ __launch_bounds__(256, 2) void grad_kernel(
    const __bf16* __restrict__ Rg, const __bf16* __restrict__ Sg,
    const __bf16* __restrict__ Tg,
    float* __restrict__ lse, __bf16* __restrict__ Gout) {
  const int bid = blockIdx.x;
  const int slot = bid >> 3;
  const int bh = (bid & 7) * 4 + (slot >> 4);
  const int qt = slot & 15;
  const int tid = threadIdx.x, l = tid & 63, w = tid >> 6;
  const int l31 = l & 31, hi = l >> 5;
  const int q0 = qt * 128 + w * 32;
  __shared__ __align__(16) char sT[2][8192];

  // resident operand as 32x32x16 B-fragments: B[n=l31][k=16ks+8hi+j]
  bf16x8 bres[4];
#pragma unroll
  for (int ks = 0; ks < 4; ++ks)
    bres[ks] = *(const bf16x8*)(
        Rg + ((size_t)bh * L + q0 + l31) * Z + ks * 16 + hi * 8);

  f32x16 pv[2];
#pragma unroll
  for (int zt = 0; zt < 2; ++zt)
#pragma unroll
    for (int i = 0; i < 16; ++i) pv[zt][i] = 0.f;
  float li = 0.f;

  const __bf16* __restrict__ Sbase =
      Sg + (size_t)bh * L * Z + (size_t)l31 * Z + hi * 8;
  const __bf16* __restrict__ Tbase = Tg + (size_t)bh * Z * L;

  stage_async<2>(Tbase, L, sT[0], tid);
  bf16x8 av[8];
#pragma unroll
  for (int nt = 0; nt < 2; ++nt)
#pragma unroll
    for (int ks = 0; ks < 4; ++ks)
      av[nt * 4 + ks] = *(const bf16x8*)(Sbase + (size_t)(nt * 32) * Z + ks * 16);
  __syncthreads();

  for (int kt = 0; kt < 32; ++kt) {
    const int cur = kt & 1, nxt = cur ^ 1;
    if (kt < 31) stage_async<2>(Tbase + (kt + 1) * 64, L, sT[nxt], tid);
    // prefetch PV B-frags for the CURRENT tile (staged last iter, post-barrier)
    bf16x8 bt[8];
#pragma unroll
    for (int kc = 0; kc < 4; ++kc) {
      bt[2 * kc]     = rfrag(sT[cur], l31,      2 * kc + hi);
      bt[2 * kc + 1] = rfrag(sT[cur], 32 + l31, 2 * kc + hi);
    }
    // St[c][q] = sum_z streamed[c][z] * resident[q][z]  (log2-domain scores)
    f32x16 st[2];
#pragma unroll
    for (int i = 0; i < 16; ++i) { st[0][i] = 0.f; st[1][i] = 0.f; }
#pragma unroll
    for (int ks = 0; ks < 4; ++ks) {
      st[0] = __builtin_amdgcn_mfma_f32_32x32x16_bf16(av[ks], bres[ks], st[0], 0, 0, 0);
      st[1] = __builtin_amdgcn_mfma_f32_32x32x16_bf16(av[4 + ks], bres[ks], st[1], 0, 0, 0);
    }
    // reload av for kt+1 now that St consumed them (latency hidden by exp+PV)
    if (kt < 31) {
#pragma unroll
      for (int nt = 0; nt < 2; ++nt)
#pragma unroll
        for (int ks = 0; ks < 4; ++ks)
          av[nt * 4 + ks] = *(const bf16x8*)(
              Sbase + (size_t)((kt + 1) * 64 + nt * 32) * Z + ks * 16);
    }
    // P = 2^St (fixed max = 0), packed as PV A-frags
    uint32_t P32[2][8];
    float lsn = 0.f;
#pragma unroll
    for (int nt = 0; nt < 2; ++nt)
#pragma unroll
      for (int i = 0; i < 8; ++i) {
        float e0 = EXP2(st[nt][2 * i]);
        float e1 = EXP2(st[nt][2 * i + 1]);
        if (MODE == 0) lsn += e0 + e1;
        union { __bf16 hh[2]; uint32_t u; } pk;
        pk.hh[0] = (__bf16)e0; pk.hh[1] = (__bf16)e1;
        P32[nt][i] = pk.u;
      }
    if (MODE == 0) li += lsn;
    // PV: D[q][z] += P[q][c] * T[c][z]
#pragma unroll
    for (int kc = 0; kc < 4; ++kc) {
      union { uint32_t u[4]; bf16x8 v; } a;
#pragma unroll
      for (int i = 0; i < 4; ++i) a.u[i] = P32[kc >> 1][4 * (kc & 1) + i];
      pv[0] = __builtin_amdgcn_mfma_f32_32x32x16_bf16(a.v, bt[2 * kc], pv[0], 0, 0, 0);
      pv[1] = __builtin_amdgcn_mfma_f32_32x32x16_bf16(a.v, bt[2 * kc + 1], pv[1], 0, 0, 0);
    }
    __syncthreads();
  }
  if (MODE == 0) li += __shfl_xor(li, 32);
  const int b = bh >> 4, head = bh & (H - 1);
#pragma unroll
  for (int r = 0; r < 16; ++r) {
    const int qoff = (r & 3) + 8 * (r >> 2) + 4 * hi;   // C-layout row
    float scl = 1.f;
    if (MODE == 0)
      scl = 1.f / __int_as_float(
                __builtin_amdgcn_ds_bpermute(4 * qoff, __float_as_int(li)));
    const size_t orow = ((size_t)b * L + q0 + qoff) * HZ + head * Z;
    Gout[orow + l31]      = (__bf16)(-pv[0][r] * scl);
    Gout[orow + 32 + l31] = (__bf16)(-pv[1][r] * scl);
  }
  if (MODE == 0 && hi == 0)
    lse[(size_t)bh * L + q0 + l31] = __logf(li);
}

// ---------------------------------------------------------------------------
// kpt[row][pos] *= exp(-lse[true_l(pos)])  (in place; pos is l-permuted)
// ---------------------------------------------------------------------------
__global__ __launch_bounds__(256) void kscale_kernel(__bf16* __restrict__ kpt,
                                                     const float* __restrict__ lse) {
  int idx = blockIdx.x * 256 + threadIdx.x;
  int row = idx >> 9;                          // bh*64 + z
  int pos4 = (idx & 511) << 2;
  int bh = row >> 6;
  int lbase = (pos4 & ~15) + (((pos4 >> 2) & 1) << 3) + (((pos4 >> 3) & 1) << 2);
  float4 ls = *(const float4*)(lse + (size_t)bh * L + lbase);
  __bf16* p = kpt + (size_t)row * L + pos4;
  union { __bf16 hh[4]; uint2 u; } v;
  v.u = *(uint2*)p;
  v.hh[0] = (__bf16)((float)v.hh[0] * __expf(-ls.x));
  v.hh[1] = (__bf16)((float)v.hh[1] * __expf(-ls.y));
  v.hh[2] = (__bf16)((float)v.hh[2] * __expf(-ls.z));
  v.hh[3] = (__bf16)((float)v.hh[3] * __expf(-ls.w));
  *(uint2*)p = v.u;
}

// ---------------------------------------------------------------------------
// en[b] = -(1/beta) * sum_{h,q} lse[b,h,q]
// ---------------------------------------------------------------------------
__global__ __launch_bounds__(256) void energy_kernel(
    const float* __restrict__ lse_ws, const float* __restrict__ beta_p,
    float* __restrict__ out) {
  const int b = blockIdx.x;
  const float* p = lse_ws + (size_t)b * H * L;
  float sum = 0.f;
  for (int i = threadIdx.x; i < H * L; i += 256) sum += p[i];
#pragma unroll
  for (int off = 1; off < 64; off <<= 1) sum += __shfl_xor(sum, off, 64);
  __shared__ float wsum[4];
  if ((threadIdx.x & 63) == 0) wsum[threadIdx.x >> 6] = sum;
  __syncthreads();
  if (threadIdx.x == 0)
    out[b] = -(wsum[0] + wsum[1] + wsum[2] + wsum[3]) / beta_p[0];
}

// ---------------------------------------------------------------------------
// gx[m][d] = sum_hz Gkp[m][hz]*Wk[hz][d] + Gqp[m][hz]*Wq[hz][d]
// 128x128 tile, K=2048 (two stacked 1024 sources), async double-buffered.
// ---------------------------------------------------------------------------
__global__ __launch_bounds__(256, 2) void gx_kernel(
    const __bf16* __restrict__ Gkp, const __bf16* __restrict__ Gqp,
    const __bf16* __restrict__ Wkt, const __bf16* __restrict__ Wqt,
    float* __restrict__ gx) {
  const int n0 = blockIdx.x * 128, m0 = blockIdx.y * 128;
  const int tid = threadIdx.x, l = tid & 63, w = tid >> 6;
  const int l31 = l & 31, hi = l >> 5;
  const int mh = w >> 1, nh = w & 1;
  __shared__ __align__(16) char sA[2][16384], sB[2][16384];

  f32x16 acc[2][2];
#pragma unroll
  for (int mi = 0; mi < 2; ++mi)
#pragma unroll
    for (int ni = 0; ni < 2; ++ni)
#pragma unroll
      for (int i = 0; i < 16; ++i) acc[mi][ni][i] = 0.f;

  stage_async<4>(Gkp + (size_t)m0 * HZ, HZ, sA[0], tid);
  stage_async<4>(Wkt + (size_t)n0 * HZ, HZ, sB[0], tid);
  __syncthreads();

  for (int kk = 0; kk < 32; ++kk) {
    const int cur = kk & 1, nxt = cur ^ 1;
    if (kk < 31) {
      const int kn = kk + 1;
      const __bf16* __restrict__ An = (kn < 16 ? Gkp : Gqp);
      const __bf16* __restrict__ Bn = (kn < 16 ? Wkt : Wqt);
      const int k0 = (kn & 15) * 64;
      stage_async<4>(An + (size_t)m0 * HZ + k0, HZ, sA[nxt], tid);
      stage_async<4>(Bn + (size_t)n0 * HZ + k0, HZ, sB[nxt], tid);
    }
#pragma unroll
    for (int ks = 0; ks < 4; ++ks) {
      bf16x8 am[2], bn[2];
#pragma unroll
      for (int mi = 0; mi < 2; ++mi)
        am[mi] = rfrag(sA[cur], mh * 64 + mi * 32 + l31, 2 * ks + hi);
#pragma unroll
      for (int ni = 0; ni < 2; ++ni)
        bn[ni] = rfrag(sB[cur], nh * 64 + ni * 32 + l31, 2 * ks + hi);
#pragma unroll
      for (int mi = 0; mi < 2; ++mi)
#pragma unroll
        for (int ni = 0; ni < 2; ++ni)
          acc[mi][ni] = __builtin_amdgcn_mfma_f32_32x32x16_bf16(
              am[mi], bn[ni], acc[mi][ni], 0, 0, 0);
    }
    __syncthreads();
  }
#pragma unroll
  for (int mi = 0; mi < 2; ++mi)
#pragma unroll
    for (int ni = 0; ni < 2; ++ni) {
      const int n = n0 + nh * 64 + ni * 32 + l31;
#pragma unroll
      for (int r = 0; r < 16; ++r) {
        const int m = m0 + mh * 64 + mi * 32 + (r & 3) + 8 * (r >> 2) + 4 * hi;
        gx[(size_t)m * D + n] = acc[mi][ni][r];
      }
    }
}

// ---------------------------------------------------------------------------
extern "C" void kernel_launch(void* const* d_in, const int* in_sizes, int n_in,
                              void* d_out, int out_size, void* d_ws, size_t ws_size,
                              hipStream_t stream) {
  const float* x    = (const float*)d_in[0];
  const float* Wq   = (const float*)d_in[1];
  const float* Wk   = (const float*)d_in[2];
  const float* beta = (const float*)d_in[3];
  float* out = (float*)d_out;

  char* ws = (char*)d_ws;
  __bf16* xb  = (__bf16*)(ws);                         // 8 MB
  __bf16* Wkb = (__bf16*)(ws + (8ull  << 20));         // 2 MB
  __bf16* Wqb = (__bf16*)(ws + (10ull << 20));         // 2 MB
  __bf16* Wkt = (__bf16*)(ws + (12ull << 20));         // 2 MB
  __bf16* Wqt = (__bf16*)(ws + (14ull << 20));         // 2 MB
  __bf16* kp  = (__bf16*)(ws + (16ull << 20));         // 8 MB (scaled)
  __bf16* qp  = (__bf16*)(ws + (24ull << 20));         // 8 MB (scaled)
  __bf16* kpt = (__bf16*)(ws + (32ull << 20));         // 8 MB (l-perm, unscaled)
  __bf16* qpt = (__bf16*)(ws + (40ull << 20));         // 8 MB (l-perm, unscaled)
  __bf16* Gkp = (__bf16*)(ws + (48ull << 20));         // 8 MB
  __bf16* Gqp = (__bf16*)(ws + (56ull << 20));         // 8 MB
  float*  lse = (float*)(ws + (64ull << 20));          // 256 KB

  cvt_kernel<<<4096, 256, 0, stream>>>(x, xb, 1048576);
  wt_kernel<<<dim3(16, 16, 2), 256, 0, stream>>>(Wk, Wq, Wkb, Wqb, Wkt, Wqt);
  proj_kernel<<<dim3(8, 32, 2), 256, 0, stream>>>(xb, Wkb, Wqb, beta, kp, qp, kpt, qpt);
  grad_kernel<0><<<512, 256, 0, stream>>>(kp, qp, qpt, lse, Gkp);
  kscale_kernel<<<4096, 256, 0, stream>>>(kpt, lse);
  grad_kernel<1><<<512, 256, 0, stream>>>(qp, kp, kpt, lse, Gqp);
  energy_kernel<<<2, 256, 0, stream>>>(lse, beta, out);
  gx_kernel<<<dim3(8, 32), 256, 0, stream>>>(Gkp, Gqp, Wkt, Wqt, out + 2);
}